// Round 1
// baseline (131.719 us; speedup 1.0000x reference)
//
#include <hip/hip_runtime.h>
#include <hip/hip_bf16.h>

#define VOCAB 50257
#define FEAT 512
#define NTOK (32 * 4096)
#define EPS 1e-12f

// ---------------------------------------------------------------------------
// Kernel 1: transpose W [FEAT, VOCAB] (row-major) -> Wt [VOCAB, FEAT]
// Tiled 32x32 with +1 pad to avoid LDS bank conflicts; coalesced on both
// global read (inner dim v) and global write (inner dim f).
// ---------------------------------------------------------------------------
__global__ __launch_bounds__(256) void transpose_W(const float* __restrict__ W,
                                                   float* __restrict__ Wt) {
    __shared__ float tile[32][33];
    const int tx = threadIdx.x;          // 0..31
    const int ty = threadIdx.y;          // 0..7
    const int v0 = blockIdx.x * 32;
    const int f0 = blockIdx.y * 32;      // FEAT=512 divisible by 32 -> no f bound check

    const int v_in = v0 + tx;
#pragma unroll
    for (int k = 0; k < 4; ++k) {
        const int f = f0 + ty + k * 8;
        if (v_in < VOCAB)
            tile[ty + k * 8][tx] = W[(long)f * VOCAB + v_in];
    }
    __syncthreads();

    const int f_out = f0 + tx;
#pragma unroll
    for (int k = 0; k < 4; ++k) {
        const int v = v0 + ty + k * 8;
        if (v < VOCAB)
            Wt[(long)v * FEAT + f_out] = tile[tx][ty + k * 8];
    }
}

// ---------------------------------------------------------------------------
// Kernel 2: one wave (64 lanes) per token. Contiguous Wt row gather,
// bias add, wave-level sum-of-squares reduction, normalize, coalesced store.
// Each lane handles 8 floats as 2x float4.
// ---------------------------------------------------------------------------
__global__ __launch_bounds__(256) void encode_from_Wt(const int* __restrict__ ids,
                                                      const float* __restrict__ Wt,
                                                      const float* __restrict__ bias,
                                                      float* __restrict__ out) {
    const int wave = (int)((blockIdx.x * (long)blockDim.x + threadIdx.x) >> 6);
    const int lane = threadIdx.x & 63;
    if (wave >= NTOK) return;

    const int id = ids[wave];
    const float4* __restrict__ src = (const float4*)(Wt + (long)id * FEAT);
    const float4* __restrict__ bb  = (const float4*)bias;

    float4 x0 = src[lane];        // feats [0,256)
    float4 x1 = src[64 + lane];   // feats [256,512)
    const float4 b0 = bb[lane];
    const float4 b1 = bb[64 + lane];

    x0.x += b0.x; x0.y += b0.y; x0.z += b0.z; x0.w += b0.w;
    x1.x += b1.x; x1.y += b1.y; x1.z += b1.z; x1.w += b1.w;

    float s = x0.x * x0.x + x0.y * x0.y + x0.z * x0.z + x0.w * x0.w
            + x1.x * x1.x + x1.y * x1.y + x1.z * x1.z + x1.w * x1.w;

#pragma unroll
    for (int off = 32; off > 0; off >>= 1)
        s += __shfl_xor(s, off, 64);

    const float inv = 1.0f / fmaxf(sqrtf(s), EPS);

    x0.x *= inv; x0.y *= inv; x0.z *= inv; x0.w *= inv;
    x1.x *= inv; x1.y *= inv; x1.z *= inv; x1.w *= inv;

    float4* __restrict__ dst = (float4*)(out + (long)wave * FEAT);
    dst[lane]      = x0;
    dst[64 + lane] = x1;
}

// ---------------------------------------------------------------------------
// Fallback (ws too small): gather directly from W with strided reads.
// Correct but uncoalesced; only used if workspace < 103 MB.
// ---------------------------------------------------------------------------
__global__ __launch_bounds__(256) void encode_direct(const int* __restrict__ ids,
                                                     const float* __restrict__ W,
                                                     const float* __restrict__ bias,
                                                     float* __restrict__ out) {
    const int wave = (int)((blockIdx.x * (long)blockDim.x + threadIdx.x) >> 6);
    const int lane = threadIdx.x & 63;
    if (wave >= NTOK) return;

    const int id = ids[wave];
    float x[8];
    float s = 0.0f;
#pragma unroll
    for (int j = 0; j < 8; ++j) {
        const int f = lane * 4 + (j & 3) + (j >> 2) * 256;
        x[j] = W[(long)f * VOCAB + id] + bias[f];
        s += x[j] * x[j];
    }
#pragma unroll
    for (int off = 32; off > 0; off >>= 1)
        s += __shfl_xor(s, off, 64);

    const float inv = 1.0f / fmaxf(sqrtf(s), EPS);

    float4 o0 = make_float4(x[0] * inv, x[1] * inv, x[2] * inv, x[3] * inv);
    float4 o1 = make_float4(x[4] * inv, x[5] * inv, x[6] * inv, x[7] * inv);
    float4* __restrict__ dst = (float4*)(out + (long)wave * FEAT);
    dst[lane]      = o0;
    dst[64 + lane] = o1;
}

extern "C" void kernel_launch(void* const* d_in, const int* in_sizes, int n_in,
                              void* d_out, int out_size, void* d_ws, size_t ws_size,
                              hipStream_t stream) {
    const int*   ids  = (const int*)d_in[0];
    const float* W    = (const float*)d_in[1];
    const float* bias = (const float*)d_in[2];
    float*       out  = (float*)d_out;

    const size_t wt_bytes = (size_t)VOCAB * FEAT * sizeof(float);

    const int waves_per_block = 4;                       // 256 threads
    const int nblocks = NTOK / waves_per_block;          // 131072/4 = 32768

    if (ws_size >= wt_bytes) {
        float* Wt = (float*)d_ws;
        dim3 tgrid((VOCAB + 31) / 32, FEAT / 32);        // (1571, 16)
        dim3 tblock(32, 8);
        transpose_W<<<tgrid, tblock, 0, stream>>>(W, Wt);
        encode_from_Wt<<<nblocks, 256, 0, stream>>>(ids, Wt, bias, out);
    } else {
        encode_direct<<<nblocks, 256, 0, stream>>>(ids, W, bias, out);
    }
}